// Round 1
// baseline (120.655 us; speedup 1.0000x reference)
//
#include <hip/hip_runtime.h>
#include <hip/hip_bf16.h>

typedef __attribute__((ext_vector_type(4))) float f32x4;
typedef __attribute__((ext_vector_type(8))) short bf16x8;

#define BK 32
#define LDA 40    // padded LDS stride (elems) for 128x32 staging tiles
#define LDC 136   // padded LDS stride for 128x128 transpose buffer

static __device__ __forceinline__ unsigned short f2bf(float f) {
    union { float f; unsigned int u; } v; v.f = f;
    unsigned int u = v.u;
    u += 0x7fffu + ((u >> 16) & 1u);   // round-to-nearest-even
    return (unsigned short)(u >> 16);
}

__global__ void convert_f32_bf16(const float* __restrict__ src,
                                 unsigned short* __restrict__ dst, int n4) {
    int i = blockIdx.x * blockDim.x + threadIdx.x;
    if (i < n4) {
        float4 v = reinterpret_cast<const float4*>(src)[i];
        ushort4 o;
        o.x = f2bf(v.x); o.y = f2bf(v.y); o.z = f2bf(v.z); o.w = f2bf(v.w);
        reinterpret_cast<ushort4*>(dst)[i] = o;
    }
}

// Wt[n][k] = W[k][n], 256x256
__global__ void transpose_w_bf16(const float* __restrict__ W,
                                 unsigned short* __restrict__ Wt) {
    int k = blockIdx.x;
    int n = threadIdx.x;
    Wt[n * 256 + k] = f2bf(W[k * 256 + n]);
}

// GEMM1: h = x @ W.  A = x_bf16 [32768][256] row-major, Bt = Wt [256][256]
// (n-major, k contiguous). Output written TRANSPOSED per batch:
// Ht[b][d][j] = h[b*512+j][d],  b = node_row/512.
__global__ __launch_bounds__(256) void gemm1_xw(
    const unsigned short* __restrict__ A,
    const unsigned short* __restrict__ Bt,
    unsigned short* __restrict__ Ht)
{
    __shared__ __align__(16) unsigned short smem[128 * LDC]; // 34816 B, unions staging + transpose
    unsigned short* sA = smem;                // 128*LDA
    unsigned short* sB = smem + 128 * LDA;    // 128*LDA

    const int tid  = threadIdx.x;
    const int lane = tid & 63;
    const int wave = tid >> 6;
    const int wr   = (wave >> 1) * 64;
    const int wc   = (wave & 1) * 64;
    const int l15  = lane & 15;
    const int quad = lane >> 4;

    const int mBase = blockIdx.x * 128;
    const int nBase = blockIdx.y * 128;
    const int K = 256;

    f32x4 acc[4][4];
#pragma unroll
    for (int i = 0; i < 4; i++)
#pragma unroll
        for (int j = 0; j < 4; j++) acc[i][j] = (f32x4){0.f, 0.f, 0.f, 0.f};

    const int srow = tid >> 1;
    const int sseg = (tid & 1) * 16;

    for (int k0 = 0; k0 < K; k0 += BK) {
        __syncthreads();
        {
            const uint4* ga = reinterpret_cast<const uint4*>(
                A + (size_t)(mBase + srow) * K + k0 + sseg);
            uint4 a0 = ga[0], a1 = ga[1];
            const uint4* gb = reinterpret_cast<const uint4*>(
                Bt + (size_t)(nBase + srow) * K + k0 + sseg);
            uint4 b0 = gb[0], b1 = gb[1];
            *reinterpret_cast<uint4*>(sA + srow * LDA + sseg)     = a0;
            *reinterpret_cast<uint4*>(sA + srow * LDA + sseg + 8) = a1;
            *reinterpret_cast<uint4*>(sB + srow * LDA + sseg)     = b0;
            *reinterpret_cast<uint4*>(sB + srow * LDA + sseg + 8) = b1;
        }
        __syncthreads();

        bf16x8 af[4], bfr[4];
#pragma unroll
        for (int mi = 0; mi < 4; mi++)
            af[mi] = *reinterpret_cast<const bf16x8*>(sA + (wr + mi * 16 + l15) * LDA + quad * 8);
#pragma unroll
        for (int ni = 0; ni < 4; ni++)
            bfr[ni] = *reinterpret_cast<const bf16x8*>(sB + (wc + ni * 16 + l15) * LDA + quad * 8);
#pragma unroll
        for (int mi = 0; mi < 4; mi++)
#pragma unroll
            for (int ni = 0; ni < 4; ni++)
                acc[mi][ni] = __builtin_amdgcn_mfma_f32_16x16x32_bf16(
                    af[mi], bfr[ni], acc[mi][ni], 0, 0, 0);
    }

    // Epilogue: transpose through LDS, write Ht[b][d][j] coalesced along j.
    __syncthreads();
    unsigned short* sC = smem;
#pragma unroll
    for (int mi = 0; mi < 4; mi++) {
#pragma unroll
        for (int ni = 0; ni < 4; ni++) {
            int row = wr + mi * 16 + quad * 4;  // m (node) dim
            int col = wc + ni * 16 + l15;       // n (feature) dim
            ushort4 p;
            p.x = f2bf(acc[mi][ni][0]);
            p.y = f2bf(acc[mi][ni][1]);
            p.z = f2bf(acc[mi][ni][2]);
            p.w = f2bf(acc[mi][ni][3]);
            *reinterpret_cast<ushort4*>(sC + col * LDC + row) = p;
        }
    }
    __syncthreads();

    const int b     = blockIdx.x >> 2;
    const int jBase = (blockIdx.x & 3) * 128;
    const int rloc  = tid >> 4;   // 0..15
    const int chunk = tid & 15;   // 0..15
#pragma unroll
    for (int p = 0; p < 8; p++) {
        int col = p * 16 + rloc;  // feature d local
        uint4 v = *reinterpret_cast<const uint4*>(sC + col * LDC + chunk * 8);
        size_t off = ((size_t)b * 256 + (nBase + col)) * 512 + jBase + chunk * 8;
        *reinterpret_cast<uint4*>(Ht + off) = v;
    }
}

// GEMM2: out[b] = adj @ h[b].  A = adj_bf16 [512][512] (shared across batch),
// Bt = Ht[b] [256][512] (n-major, k contiguous). Out fp32 [b*512+i][d].
__global__ __launch_bounds__(256) void gemm2_adj(
    const unsigned short* __restrict__ Adj,
    const unsigned short* __restrict__ Ht,
    float* __restrict__ Out)
{
    __shared__ __align__(16) unsigned short smem[2 * 128 * LDA];
    unsigned short* sA = smem;
    unsigned short* sB = smem + 128 * LDA;

    const int tid  = threadIdx.x;
    const int lane = tid & 63;
    const int wave = tid >> 6;
    const int wr   = (wave >> 1) * 64;
    const int wc   = (wave & 1) * 64;
    const int l15  = lane & 15;
    const int quad = lane >> 4;

    const int mBase = blockIdx.x * 128;   // node row i
    const int nBase = blockIdx.y * 128;   // feature d
    const int b     = blockIdx.z;
    const int K = 512;

    const unsigned short* BtB = Ht + (size_t)b * 256 * 512;

    f32x4 acc[4][4];
#pragma unroll
    for (int i = 0; i < 4; i++)
#pragma unroll
        for (int j = 0; j < 4; j++) acc[i][j] = (f32x4){0.f, 0.f, 0.f, 0.f};

    const int srow = tid >> 1;
    const int sseg = (tid & 1) * 16;

    for (int k0 = 0; k0 < K; k0 += BK) {
        __syncthreads();
        {
            const uint4* ga = reinterpret_cast<const uint4*>(
                Adj + (size_t)(mBase + srow) * K + k0 + sseg);
            uint4 a0 = ga[0], a1 = ga[1];
            const uint4* gb = reinterpret_cast<const uint4*>(
                BtB + (size_t)(nBase + srow) * K + k0 + sseg);
            uint4 b0 = gb[0], b1 = gb[1];
            *reinterpret_cast<uint4*>(sA + srow * LDA + sseg)     = a0;
            *reinterpret_cast<uint4*>(sA + srow * LDA + sseg + 8) = a1;
            *reinterpret_cast<uint4*>(sB + srow * LDA + sseg)     = b0;
            *reinterpret_cast<uint4*>(sB + srow * LDA + sseg + 8) = b1;
        }
        __syncthreads();

        bf16x8 af[4], bfr[4];
#pragma unroll
        for (int mi = 0; mi < 4; mi++)
            af[mi] = *reinterpret_cast<const bf16x8*>(sA + (wr + mi * 16 + l15) * LDA + quad * 8);
#pragma unroll
        for (int ni = 0; ni < 4; ni++)
            bfr[ni] = *reinterpret_cast<const bf16x8*>(sB + (wc + ni * 16 + l15) * LDA + quad * 8);
#pragma unroll
        for (int mi = 0; mi < 4; mi++)
#pragma unroll
            for (int ni = 0; ni < 4; ni++)
                acc[mi][ni] = __builtin_amdgcn_mfma_f32_16x16x32_bf16(
                    af[mi], bfr[ni], acc[mi][ni], 0, 0, 0);
    }

#pragma unroll
    for (int mi = 0; mi < 4; mi++) {
        int rbase = mBase + wr + mi * 16 + quad * 4;
#pragma unroll
        for (int ni = 0; ni < 4; ni++) {
            int cg = nBase + wc + ni * 16 + l15;
            size_t base = ((size_t)b * 512 + rbase) * 256 + cg;
            Out[base]       = acc[mi][ni][0];
            Out[base + 256] = acc[mi][ni][1];
            Out[base + 512] = acc[mi][ni][2];
            Out[base + 768] = acc[mi][ni][3];
        }
    }
}

extern "C" void kernel_launch(void* const* d_in, const int* in_sizes, int n_in,
                              void* d_out, int out_size, void* d_ws, size_t ws_size,
                              hipStream_t stream) {
    const float* x   = (const float*)d_in[0];
    // d_in[1] = batch ids (unused; layout is contiguous blocks by construction)
    const float* W   = (const float*)d_in[2];
    const float* Adj = (const float*)d_in[3];
    float* out = (float*)d_out;

    unsigned short* xb   = (unsigned short*)d_ws;       // 8388608 elems
    unsigned short* adjb = xb + 8388608;                // 262144
    unsigned short* wtb  = adjb + 262144;               // 65536
    unsigned short* ht   = wtb + 65536;                 // 8388608
    // total ws: 34,209,792 bytes

    convert_f32_bf16<<<8192, 256, 0, stream>>>(x, xb, 2097152);
    convert_f32_bf16<<<256, 256, 0, stream>>>(Adj, adjb, 65536);
    transpose_w_bf16<<<256, 256, 0, stream>>>(W, wtb);
    gemm1_xw<<<dim3(256, 2), 256, 0, stream>>>(xb, wtb, ht);
    gemm2_adj<<<dim3(4, 2, 64), 256, 0, stream>>>(adjb, ht, out);
}

// Round 2
// 116.176 us; speedup vs baseline: 1.0385x; 1.0385x over previous
//
#include <hip/hip_runtime.h>
#include <hip/hip_bf16.h>

typedef __attribute__((ext_vector_type(4))) float f32x4;
typedef __attribute__((ext_vector_type(8))) short bf16x8;

#define BK 32
#define LDC 136   // padded LDS stride for 128x128 transpose buffer (gemm1 epilogue)

typedef const __attribute__((address_space(1))) unsigned int* gp_t;
typedef __attribute__((address_space(3))) unsigned int* lp_t;

// Async global->LDS copy, 16B per lane. LDS dest = base + lane*16 (HW).
static __device__ __forceinline__ void glds16(void* lds, const void* g) {
    __builtin_amdgcn_global_load_lds((gp_t)g, (lp_t)lds, 16, 0, 0);
}

static __device__ __forceinline__ unsigned short f2bf(float f) {
    union { float f; unsigned int u; } v; v.f = f;
    unsigned int u = v.u;
    u += 0x7fffu + ((u >> 16) & 1u);   // round-to-nearest-even
    return (unsigned short)(u >> 16);
}

// One dispatch: convert x (blocks 0..8191), convert adj (8192..8447),
// transpose+convert W (8448..8703).
__global__ void prep(const float* __restrict__ x, const float* __restrict__ adj,
                     const float* __restrict__ W,
                     unsigned short* __restrict__ xb,
                     unsigned short* __restrict__ adjb,
                     unsigned short* __restrict__ wtb) {
    int b = blockIdx.x;
    int t = threadIdx.x;
    if (b < 8448) {
        const float* src = (b < 8192) ? x : adj;
        unsigned short* dst = (b < 8192) ? xb : adjb;
        int i = (b < 8192) ? (b * 256 + t) : ((b - 8192) * 256 + t);
        float4 v = reinterpret_cast<const float4*>(src)[i];
        ushort4 o;
        o.x = f2bf(v.x); o.y = f2bf(v.y); o.z = f2bf(v.z); o.w = f2bf(v.w);
        reinterpret_cast<ushort4*>(dst)[i] = o;
    } else {
        int k = b - 8448;                       // 0..255
        wtb[t * 256 + k] = f2bf(W[k * 256 + t]); // Wt[n][k] = W[k][n]
    }
}

// GEMM1: h = x @ W.  A = xb [32768][256], Bt = wtb [256][256] (n-major,k-contig).
// Output written TRANSPOSED per batch: Ht[b][d][j] = h[b*512+j][d].
__global__ __launch_bounds__(256) void gemm1_xw(
    const unsigned short* __restrict__ A,
    const unsigned short* __restrict__ Bt,
    unsigned short* __restrict__ Ht)
{
    __shared__ __align__(16) unsigned short smem[128 * LDC]; // 34816 B; unions staging+transpose
    unsigned short* sA = smem;            // [128][32] unpadded (global_load_lds layout)
    unsigned short* sB = smem + 4096;     // [128][32]

    const int tid  = threadIdx.x;
    const int lane = tid & 63;
    const int wave = tid >> 6;
    const int wr   = (wave >> 1) * 64;
    const int wc   = (wave & 1) * 64;
    const int l15  = lane & 15;
    const int quad = lane >> 4;

    const int mBase = blockIdx.x * 128;
    const int nBase = blockIdx.y * 128;
    const int K = 256;

    // staging address components: chunk = wave*2+c covers 16 rows; lane covers
    // row chunk*16 + lane/4, 8-elem segment (lane%4)*8.
    const int rOf = lane >> 2;
    const int sg  = (lane & 3) * 8;

    f32x4 acc[4][4];
#pragma unroll
    for (int i = 0; i < 4; i++)
#pragma unroll
        for (int j = 0; j < 4; j++) acc[i][j] = (f32x4){0.f, 0.f, 0.f, 0.f};

    for (int k0 = 0; k0 < K; k0 += BK) {
        __syncthreads();
#pragma unroll
        for (int c = 0; c < 2; c++) {
            int chunk = wave * 2 + c;
            int row = chunk * 16 + rOf;
            glds16(sA + chunk * 512, A + (size_t)(mBase + row) * K + k0 + sg);
            glds16(sB + chunk * 512, Bt + (size_t)(nBase + row) * K + k0 + sg);
        }
        __syncthreads();

        bf16x8 af[4], bfr[4];
#pragma unroll
        for (int mi = 0; mi < 4; mi++)
            af[mi] = *reinterpret_cast<const bf16x8*>(sA + (wr + mi * 16 + l15) * 32 + quad * 8);
#pragma unroll
        for (int ni = 0; ni < 4; ni++)
            bfr[ni] = *reinterpret_cast<const bf16x8*>(sB + (wc + ni * 16 + l15) * 32 + quad * 8);
#pragma unroll
        for (int mi = 0; mi < 4; mi++)
#pragma unroll
            for (int ni = 0; ni < 4; ni++)
                acc[mi][ni] = __builtin_amdgcn_mfma_f32_16x16x32_bf16(
                    af[mi], bfr[ni], acc[mi][ni], 0, 0, 0);
    }

    // Epilogue: transpose through LDS, write Ht[b][d][j] coalesced along j.
    __syncthreads();
    unsigned short* sC = smem;
#pragma unroll
    for (int mi = 0; mi < 4; mi++) {
#pragma unroll
        for (int ni = 0; ni < 4; ni++) {
            int row = wr + mi * 16 + quad * 4;  // m (node) dim
            int col = wc + ni * 16 + l15;       // n (feature) dim
            ushort4 p;
            p.x = f2bf(acc[mi][ni][0]);
            p.y = f2bf(acc[mi][ni][1]);
            p.z = f2bf(acc[mi][ni][2]);
            p.w = f2bf(acc[mi][ni][3]);
            *reinterpret_cast<ushort4*>(sC + col * LDC + row) = p;
        }
    }
    __syncthreads();

    const int b     = blockIdx.x >> 2;
    const int jBase = (blockIdx.x & 3) * 128;
    const int rloc  = tid >> 4;   // 0..15
    const int chunk = tid & 15;   // 0..15
#pragma unroll
    for (int p = 0; p < 8; p++) {
        int col = p * 16 + rloc;  // feature d local
        uint4 v = *reinterpret_cast<const uint4*>(sC + col * LDC + chunk * 8);
        size_t off = ((size_t)b * 256 + (nBase + col)) * 512 + jBase + chunk * 8;
        *reinterpret_cast<uint4*>(Ht + off) = v;
    }
}

// GEMM2: out[b] = adj @ h[b].  A = adjb [512][512] (shared), Bt = Ht[b]
// [256][512] (n-major,k-contig). Out fp32 [b*512+i][d].
__global__ __launch_bounds__(256) void gemm2_adj(
    const unsigned short* __restrict__ Adj,
    const unsigned short* __restrict__ Ht,
    float* __restrict__ Out)
{
    __shared__ __align__(16) unsigned short smem[2 * 4096]; // 16 KiB
    unsigned short* sA = smem;
    unsigned short* sB = smem + 4096;

    const int tid  = threadIdx.x;
    const int lane = tid & 63;
    const int wave = tid >> 6;
    const int wr   = (wave >> 1) * 64;
    const int wc   = (wave & 1) * 64;
    const int l15  = lane & 15;
    const int quad = lane >> 4;

    const int mBase = blockIdx.x * 128;   // node row i
    const int nBase = blockIdx.y * 128;   // feature d
    const int b     = blockIdx.z;
    const int K = 512;

    const unsigned short* BtB = Ht + (size_t)b * 256 * 512;

    const int rOf = lane >> 2;
    const int sg  = (lane & 3) * 8;

    f32x4 acc[4][4];
#pragma unroll
    for (int i = 0; i < 4; i++)
#pragma unroll
        for (int j = 0; j < 4; j++) acc[i][j] = (f32x4){0.f, 0.f, 0.f, 0.f};

    for (int k0 = 0; k0 < K; k0 += BK) {
        __syncthreads();
#pragma unroll
        for (int c = 0; c < 2; c++) {
            int chunk = wave * 2 + c;
            int row = chunk * 16 + rOf;
            glds16(sA + chunk * 512, Adj + (size_t)(mBase + row) * K + k0 + sg);
            glds16(sB + chunk * 512, BtB + (size_t)(nBase + row) * K + k0 + sg);
        }
        __syncthreads();

        bf16x8 af[4], bfr[4];
#pragma unroll
        for (int mi = 0; mi < 4; mi++)
            af[mi] = *reinterpret_cast<const bf16x8*>(sA + (wr + mi * 16 + l15) * 32 + quad * 8);
#pragma unroll
        for (int ni = 0; ni < 4; ni++)
            bfr[ni] = *reinterpret_cast<const bf16x8*>(sB + (wc + ni * 16 + l15) * 32 + quad * 8);
#pragma unroll
        for (int mi = 0; mi < 4; mi++)
#pragma unroll
            for (int ni = 0; ni < 4; ni++)
                acc[mi][ni] = __builtin_amdgcn_mfma_f32_16x16x32_bf16(
                    af[mi], bfr[ni], acc[mi][ni], 0, 0, 0);
    }

#pragma unroll
    for (int mi = 0; mi < 4; mi++) {
        int rbase = mBase + wr + mi * 16 + quad * 4;
#pragma unroll
        for (int ni = 0; ni < 4; ni++) {
            int cg = nBase + wc + ni * 16 + l15;
            size_t base = ((size_t)b * 512 + rbase) * 256 + cg;
            Out[base]       = acc[mi][ni][0];
            Out[base + 256] = acc[mi][ni][1];
            Out[base + 512] = acc[mi][ni][2];
            Out[base + 768] = acc[mi][ni][3];
        }
    }
}

extern "C" void kernel_launch(void* const* d_in, const int* in_sizes, int n_in,
                              void* d_out, int out_size, void* d_ws, size_t ws_size,
                              hipStream_t stream) {
    const float* x   = (const float*)d_in[0];
    // d_in[1] = batch ids (unused; layout is contiguous blocks by construction)
    const float* W   = (const float*)d_in[2];
    const float* Adj = (const float*)d_in[3];
    float* out = (float*)d_out;

    unsigned short* xb   = (unsigned short*)d_ws;       // 8388608 elems
    unsigned short* adjb = xb + 8388608;                // 262144
    unsigned short* wtb  = adjb + 262144;               // 65536
    unsigned short* ht   = wtb + 65536;                 // 8388608

    prep<<<8704, 256, 0, stream>>>(x, Adj, W, xb, adjb, wtb);
    gemm1_xw<<<dim3(256, 2), 256, 0, stream>>>(xb, wtb, ht);
    gemm2_adj<<<dim3(4, 2, 64), 256, 0, stream>>>(adjb, ht, out);
}